// Round 2
// baseline (295.252 us; speedup 1.0000x reference)
//
#include <hip/hip_runtime.h>

#define Bb 16
#define Ll 2048
#define Hh 768
#define Dd 64
#define Cc 64
#define HC 64             // h-tile width (256 B rows -> full-line coalesced out stores)
#define NT (Hh / HC)      // 12 h-tiles
#define NCH (Ll / Cc)     // 32 chunks
#define PSEG 16           // parallel scan segments
#define CPS (NCH / PSEG)  // 2 chunks per segment
#define NHT (HC / 16)     // 4 MFMA col-tiles per h-tile

typedef __attribute__((ext_vector_type(8))) short bf16x8;
typedef __attribute__((ext_vector_type(4))) float f32x4;

__device__ __forceinline__ short f2bf(float f) {
  union { float f; unsigned u; } c;
  c.f = f;
  unsigned r = (c.u + 0x7FFFu + ((c.u >> 16) & 1u)) >> 16;
  return (short)r;
}
__device__ __forceinline__ unsigned pack2(float a, float b) {
  return (unsigned)(unsigned short)f2bf(a) | ((unsigned)(unsigned short)f2bf(b) << 16);
}

// CK-style barrier: waits LDS ops only; global loads stay in flight.
__device__ __forceinline__ void sync_lds() {
  asm volatile("s_waitcnt lgkmcnt(0)\n\ts_barrier" ::: "memory");
}

// ---------------- Prep: per (b,chunk) -> bf16 E[64][64], FT[64][64], scT[64][64] ----------------
__global__ __launch_bounds__(256) void prep_kernel(const int* __restrict__ x,
                                                   const float* __restrict__ ae,
                                                   const float* __restrict__ w,
                                                   short* __restrict__ Eg,
                                                   short* __restrict__ FTg,
                                                   short* __restrict__ scTg) {
  const int tid = threadIdx.x;
  const int wv = tid >> 6, lane = tid & 63, quad = lane >> 4, lq = lane & 15;
  const int b = blockIdx.x >> 5, ch = blockIdx.x & 31;
  const size_t gb = (size_t)blockIdx.x * 4096;
  __shared__ short sE[64 * 64];   // rows i, cols d (swizzled)
  __shared__ short sWT[64 * 64];  // rows e, cols d (swizzled) = w^T
  __shared__ short sF[64 * 64];   // rows i, cols e (swizzled)

  // gather E rows -> sE + Eg;  stage w^T
  {
    const int i = tid >> 2, seg = tid & 3;
    const int idx = x[b * Ll + ch * Cc + i];
    const float4* aer = (const float4*)(ae + (size_t)idx * Dd) + seg * 4;
    float4 ev[4];
#pragma unroll
    for (int q = 0; q < 4; ++q) ev[q] = aer[q];
    uint4 pA, pB;
    pA.x = pack2(ev[0].x, ev[0].y); pA.y = pack2(ev[0].z, ev[0].w);
    pA.z = pack2(ev[1].x, ev[1].y); pA.w = pack2(ev[1].z, ev[1].w);
    pB.x = pack2(ev[2].x, ev[2].y); pB.y = pack2(ev[2].z, ev[2].w);
    pB.z = pack2(ev[3].x, ev[3].y); pB.w = pack2(ev[3].z, ev[3].w);
    *(uint4*)&sE[i * 64 + (((2 * seg) ^ (i & 7)) << 3)] = pA;
    *(uint4*)&sE[i * 64 + (((2 * seg + 1) ^ (i & 7)) << 3)] = pB;
    *(uint4*)(Eg + gb + i * 64 + seg * 16) = pA;
    *(uint4*)(Eg + gb + i * 64 + seg * 16 + 8) = pB;
    const float4* wr = (const float4*)w;
#pragma unroll
    for (int q = 0; q < 4; ++q) {
      const int fl = q * 256 + tid;
      const int d = fl >> 4, es = (fl & 15) * 4;
      const float4 v = wr[fl];
      const float vv[4] = {v.x, v.y, v.z, v.w};
#pragma unroll
      for (int c = 0; c < 4; ++c) {
        const int e = es + c;
        sWT[e * 64 + (((d >> 3) ^ (e & 7)) << 3) + (d & 7)] = f2bf(vv[c]);
      }
    }
  }
  __syncthreads();

  const int rm = wv * 16 + lq;
  bf16x8 aE[2], aW[2];
#pragma unroll
  for (int ks = 0; ks < 2; ++ks) {
    const int blk = ((ks * 4 + quad) ^ (rm & 7)) << 3;
    aE[ks] = *(const bf16x8*)&sE[rm * 64 + blk];
    aW[ks] = *(const bf16x8*)&sWT[rm * 64 + blk];
  }

  // F[i][e] = sum_d E[i][d] w[d][e]  -> sF ;  FT[e][i] -> FTg
#pragma unroll
  for (int nt = 0; nt < 4; ++nt) {
    const int rn = nt * 16 + lq;
    f32x4 accF = {}, accT = {};
#pragma unroll
    for (int ks = 0; ks < 2; ++ks) {
      const int blk = ((ks * 4 + quad) ^ (rn & 7)) << 3;
      const bf16x8 bW = *(const bf16x8*)&sWT[rn * 64 + blk];
      const bf16x8 bE = *(const bf16x8*)&sE[rn * 64 + blk];
      accF = __builtin_amdgcn_mfma_f32_16x16x32_bf16(aE[ks], bW, accF, 0, 0, 0);
      accT = __builtin_amdgcn_mfma_f32_16x16x32_bf16(aW[ks], bE, accT, 0, 0, 0);
    }
#pragma unroll
    for (int r = 0; r < 4; ++r) {
      const int i = wv * 16 + quad * 4 + r;   // m of accF
      const int e = nt * 16 + lq;
      sF[i * 64 + (((e >> 3) ^ (i & 7)) << 3) + (e & 7)] = f2bf(accF[r]);
      const int e2 = wv * 16 + quad * 4 + r;  // m of accT
      const int i2 = nt * 16 + lq;
      FTg[gb + e2 * 64 + i2] = f2bf(accT[r]);
    }
  }
  __syncthreads();

  // sc[j][i] = sum_e E[j][e] F[i][e], strict mask i<j -> scTg rows j
#pragma unroll
  for (int nt = 0; nt < 4; ++nt) {
    const int rn = nt * 16 + lq;
    f32x4 acc = {};
#pragma unroll
    for (int ks = 0; ks < 2; ++ks) {
      const int blk = ((ks * 4 + quad) ^ (rn & 7)) << 3;
      const bf16x8 bF = *(const bf16x8*)&sF[rn * 64 + blk];
      acc = __builtin_amdgcn_mfma_f32_16x16x32_bf16(aE[ks], bF, acc, 0, 0, 0);
    }
#pragma unroll
    for (int r = 0; r < 4; ++r) {
      const int j = wv * 16 + quad * 4 + r;
      const int i = nt * 16 + lq;
      scTg[gb + j * 64 + i] = f2bf(i < j ? acc[r] : 0.f);
    }
  }
}

// ---------------- State: per (tile, b, seg<PSEG-1) local segment state (f32 out) ----------------
// S_loc[b][seg][h][d] = sum over i in segment of (i+1)*bx[b,i,h] * FT[d][i]
// 1-D grid, XCD-bijective: id%8 = XCD; all 12 tiles of one (b,seg) share an XCD's L2.
__global__ __launch_bounds__(256) void state_kernel(const float* __restrict__ bx,
                                                    const short* __restrict__ FTg,
                                                    float* __restrict__ Sg) {
  const int id = blockIdx.x;            // [0, 12*Bb*(PSEG-1))
  const int t12 = id >> 3;
  const int tile = t12 % NT;
  const int g = ((t12 / NT) << 3) | (id & 7);  // [0, Bb*(PSEG-1))
  const int b = g / (PSEG - 1), seg = g % (PSEG - 1);
  const int tid = threadIdx.x;
  const int w = tid >> 6, lane = tid & 63, quad = lane >> 4, lq = lane & 15;
  const int ip = tid & 31, hg = tid >> 5;
  const int rj = w * 16 + lq;

  __shared__ short sGT[2][HC * 64];

  f32x4 accS[NHT] = {};
  float4 rGa[2], rGb[2];
  bf16x8 bD[2];

  auto load_G = [&](int ch) {
    const float* xr = bx + ((size_t)(b * Ll) + ch * Cc + 2 * ip) * Hh + tile * HC + hg * 8;
    rGa[0] = *(const float4*)(xr);
    rGa[1] = *(const float4*)(xr + 4);
    rGb[0] = *(const float4*)(xr + Hh);
    rGb[1] = *(const float4*)(xr + Hh + 4);
  };
  auto load_D = [&](int ch) {
    const size_t tb = (size_t)(b * NCH + ch) * 4096;
#pragma unroll
    for (int ks = 0; ks < 2; ++ks)
      bD[ks] = *(const bf16x8*)(FTg + tb + rj * 64 + (ks * 4 + quad) * 8);
  };

  load_G(seg * CPS);
  load_D(seg * CPS);

#pragma unroll
  for (int c = 0; c < CPS; ++c) {
    const int ch = seg * CPS + c;
    const int cur = c & 1;
    const int p0 = ch * Cc;
    {
      const float s0 = (float)(p0 + 2 * ip + 1), s1 = (float)(p0 + 2 * ip + 2);
      const float A[8] = {rGa[0].x, rGa[0].y, rGa[0].z, rGa[0].w,
                          rGa[1].x, rGa[1].y, rGa[1].z, rGa[1].w};
      const float Bv[8] = {rGb[0].x, rGb[0].y, rGb[0].z, rGb[0].w,
                           rGb[1].x, rGb[1].y, rGb[1].z, rGb[1].w};
#pragma unroll
      for (int e = 0; e < 8; ++e) {
        const int h = hg * 8 + e;
        const int sa = h * 64 + (((ip >> 2) ^ (h & 7)) << 3) + 2 * (ip & 3);
        *(unsigned*)&sGT[cur][sa] = pack2(A[e] * s0, Bv[e] * s1);
      }
    }
    if (c + 1 < CPS) load_G(ch + 1);
    sync_lds();
#pragma unroll
    for (int ht = 0; ht < NHT; ++ht) {
      const int rh = ht * 16 + lq;
#pragma unroll
      for (int ks = 0; ks < 2; ++ks) {
        const int blk = ((ks * 4 + quad) ^ (rh & 7)) << 3;
        const bf16x8 gv = *(const bf16x8*)&sGT[cur][rh * 64 + blk];
        accS[ht] = __builtin_amdgcn_mfma_f32_16x16x32_bf16(gv, bD[ks], accS[ht], 0, 0, 0);
      }
    }
    if (c + 1 < CPS) load_D(ch + 1);
  }

  float* Sr = Sg + (size_t)(b * (PSEG - 1) + seg) * (Hh * Dd);
#pragma unroll
  for (int ht = 0; ht < NHT; ++ht)
#pragma unroll
    for (int r = 0; r < 4; ++r) {
      const int h = tile * HC + ht * 16 + quad * 4 + r;
      Sr[h * 64 + w * 16 + lq] = accS[ht][r];
    }
}

// ---------------- Prefix: in-place inclusive prefix-sum of segment states over seg ----------------
__global__ __launch_bounds__(256) void prefix_kernel(float* __restrict__ Sg) {
  const int b = blockIdx.x / 48;                       // 48 blocks per b (12288 float4 / 256)
  const int v = (blockIdx.x % 48) * 256 + threadIdx.x; // float4 index within plane
  float4* base = (float4*)(Sg + (size_t)b * (PSEG - 1) * (Hh * Dd)) + v;
  const int stride = Hh * Dd / 4;
  float4 va[PSEG - 1];
#pragma unroll
  for (int s = 0; s < PSEG - 1; ++s) va[s] = base[s * stride];
  float4 acc = va[0];
#pragma unroll
  for (int s = 1; s < PSEG - 1; ++s) {
    acc.x += va[s].x; acc.y += va[s].y; acc.z += va[s].z; acc.w += va[s].w;
    base[s * stride] = acc;
  }
}

// ---------------- Scan: per (tile, b, seg) — CPS-chunk segment with prefix-state init ----------------
__global__ __launch_bounds__(256) void scan_kernel(const float* __restrict__ bx,
                                                   const short* __restrict__ Eg,
                                                   const short* __restrict__ FTg,
                                                   const short* __restrict__ scTg,
                                                   const float* __restrict__ Sg,
                                                   float* __restrict__ out) {
  const int id = blockIdx.x;            // [0, 12*Bb*PSEG)
  const int t12 = id >> 3;
  const int tile = t12 % NT;
  const int g = ((t12 / NT) << 3) | (id & 7);  // [0, Bb*PSEG)
  const int b = g >> 4, seg = g & 15;
  const int tid = threadIdx.x;
  const int w = tid >> 6, lane = tid & 63, quad = lane >> 4, lq = lane & 15;
  const int ip = tid & 31, hg = tid >> 5;
  const int rj = w * 16 + lq;

  __shared__ short sGT[2][HC * 64];
  __shared__ short sST[2][HC * 64];

  f32x4 accS[NHT] = {};
  bf16x8 aC1[2], aC2[2], bD[2];  // scT / E / FT fragments, loaded straight from global
  float4 rGa[2], rGb[2];

  auto load_G = [&](int ch) {
    const float* xr = bx + ((size_t)(b * Ll) + ch * Cc + 2 * ip) * Hh + tile * HC + hg * 8;
    rGa[0] = *(const float4*)(xr);
    rGa[1] = *(const float4*)(xr + 4);
    rGb[0] = *(const float4*)(xr + Hh);
    rGb[1] = *(const float4*)(xr + Hh + 4);
  };
  auto load_frag = [&](int ch) {
    const size_t tb = (size_t)(b * NCH + ch) * 4096;
#pragma unroll
    for (int ks = 0; ks < 2; ++ks) {
      const int o = rj * 64 + (ks * 4 + quad) * 8;
      aC1[ks] = *(const bf16x8*)(scTg + tb + o);
      aC2[ks] = *(const bf16x8*)(Eg + tb + o);
      bD[ks]  = *(const bf16x8*)(FTg + tb + o);
    }
  };

  // issue chunk-0 loads first; latency overlaps the prefix-state read below
  load_G(seg * CPS);
  load_frag(seg * CPS);

  // init accS with exclusive prefix of segment states (f32, one slice)
  if (seg > 0) {
    const float* Pr = Sg + (size_t)(b * (PSEG - 1) + (seg - 1)) * (Hh * Dd);
#pragma unroll
    for (int ht = 0; ht < NHT; ++ht)
#pragma unroll
      for (int r = 0; r < 4; ++r) {
        const int h = tile * HC + ht * 16 + quad * 4 + r;
        accS[ht][r] = Pr[h * 64 + w * 16 + lq];
      }
  }

#pragma unroll
  for (int c = 0; c < CPS; ++c) {
    const int ch = seg * CPS + c;
    const int cur = c & 1;
    const int p0 = ch * Cc;
    // stage G^T
    {
      const float s0 = (float)(p0 + 2 * ip + 1), s1 = (float)(p0 + 2 * ip + 2);
      const float A[8] = {rGa[0].x, rGa[0].y, rGa[0].z, rGa[0].w,
                          rGa[1].x, rGa[1].y, rGa[1].z, rGa[1].w};
      const float Bv[8] = {rGb[0].x, rGb[0].y, rGb[0].z, rGb[0].w,
                           rGb[1].x, rGb[1].y, rGb[1].z, rGb[1].w};
#pragma unroll
      for (int e = 0; e < 8; ++e) {
        const int h = hg * 8 + e;
        const int sa = h * 64 + (((ip >> 2) ^ (h & 7)) << 3) + 2 * (ip & 3);
        *(unsigned*)&sGT[cur][sa] = pack2(A[e] * s0, Bv[e] * s1);
      }
    }
    // stage S^T (state after chunks < ch)
#pragma unroll
    for (int ht = 0; ht < NHT; ++ht)
#pragma unroll
      for (int r = 0; r < 4; ++r) {
        const int h = ht * 16 + quad * 4 + r;
        const int d = w * 16 + lq;
        sST[cur][h * 64 + (((d >> 3) ^ (h & 7)) << 3) + (d & 7)] = f2bf(accS[ht][r]);
      }
    if (c + 1 < CPS) load_G(ch + 1);
    sync_lds();  // single barrier per chunk (double-buffered LDS)

    f32x4 accO[NHT] = {};
#pragma unroll
    for (int ht = 0; ht < NHT; ++ht) {
      const int rh = ht * 16 + lq;
#pragma unroll
      for (int ks = 0; ks < 2; ++ks) {
        const int blk = ((ks * 4 + quad) ^ (rh & 7)) << 3;
        const bf16x8 gv = *(const bf16x8*)&sGT[cur][rh * 64 + blk];
        const bf16x8 st = *(const bf16x8*)&sST[cur][rh * 64 + blk];
        accO[ht] = __builtin_amdgcn_mfma_f32_16x16x32_bf16(aC1[ks], gv, accO[ht], 0, 0, 0);
        accO[ht] = __builtin_amdgcn_mfma_f32_16x16x32_bf16(aC2[ks], st, accO[ht], 0, 0, 0);
        accS[ht] = __builtin_amdgcn_mfma_f32_16x16x32_bf16(gv, bD[ks], accS[ht], 0, 0, 0);
      }
    }
    if (c + 1 < CPS) load_frag(ch + 1);  // prefetch after consumption

    // epilogue: out = bx + accO/(j+1); 256 B-aligned full-line stores per row
#pragma unroll
    for (int ht = 0; ht < NHT; ++ht)
#pragma unroll
      for (int r = 0; r < 4; ++r) {
        const int gj = p0 + w * 16 + quad * 4 + r;
        const size_t off = ((size_t)(b * Ll) + gj) * Hh + tile * HC + ht * 16 + lq;
        out[off] = bx[off] + accO[ht][r] * (1.0f / (float)(gj + 1));
      }
  }
}

extern "C" void kernel_launch(void* const* d_in, const int* in_sizes, int n_in,
                              void* d_out, int out_size, void* d_ws, size_t ws_size,
                              hipStream_t stream) {
  (void)in_sizes; (void)n_in; (void)out_size; (void)ws_size;
  const float* bx = (const float*)d_in[0];
  const int* x = (const int*)d_in[1];
  const float* ae = (const float*)d_in[2];
  const float* w = (const float*)d_in[3];
  float* out = (float*)d_out;
  short* Eg = (short*)d_ws;                       // 512*4096 bf16 = 4 MB
  short* FTg = Eg + (size_t)512 * 4096;           // 4 MB
  short* scTg = FTg + (size_t)512 * 4096;         // 4 MB
  float* Sg = (float*)(scTg + (size_t)512 * 4096);// 16*15*768*64 f32 = 47 MB

  prep_kernel<<<Bb * NCH, 256, 0, stream>>>(x, ae, w, Eg, FTg, scTg);
  state_kernel<<<NT * Bb * (PSEG - 1), 256, 0, stream>>>(bx, FTg, Sg);
  prefix_kernel<<<Bb * 48, 256, 0, stream>>>(Sg);
  scan_kernel<<<NT * Bb * PSEG, 256, 0, stream>>>(bx, Eg, FTg, scTg, Sg, out);
}

// Round 3
// 265.949 us; speedup vs baseline: 1.1102x; 1.1102x over previous
//
#include <hip/hip_runtime.h>

#define Bb 16
#define Ll 2048
#define Hh 768
#define Dd 64
#define Cc 64
#define HC 64             // h-tile width for scan (256 B rows -> full-line stores)
#define NT (Hh / HC)      // 12 h-tiles
#define NCH (Ll / Cc)     // 32 chunks
#define NPASS (Hh / 64)   // 12 G^T passes in prep

typedef __attribute__((ext_vector_type(8))) short bf16x8;
typedef __attribute__((ext_vector_type(4))) float f32x4;

__device__ __forceinline__ short f2bf(float f) {
  union { float f; unsigned u; } c;
  c.f = f;
  unsigned r = (c.u + 0x7FFFu + ((c.u >> 16) & 1u)) >> 16;
  return (short)r;
}
__device__ __forceinline__ unsigned pack2(float a, float b) {
  return (unsigned)(unsigned short)f2bf(a) | ((unsigned)(unsigned short)f2bf(b) << 16);
}
__device__ __forceinline__ float bf2f(unsigned short s) {
  union { unsigned u; float f; } c;
  c.u = ((unsigned)s) << 16;
  return c.f;
}

// CK-style barrier: waits LDS ops only; global loads stay in flight.
__device__ __forceinline__ void sync_lds() {
  asm volatile("s_waitcnt lgkmcnt(0)\n\ts_barrier" ::: "memory");
}

// ---------------- Prep: per (b,chunk) -> bf16 E, scT (frag layout) + Schunk[768][64] ----------------
// Schunk[h,d] = sum_{i in chunk} (global_i+1)*bx[i,h]*F[i,d]   (this chunk's state contribution)
__global__ __launch_bounds__(256) void prep_kernel(const int* __restrict__ x,
                                                   const float* __restrict__ ae,
                                                   const float* __restrict__ w,
                                                   const float* __restrict__ bx,
                                                   short* __restrict__ Eg,
                                                   short* __restrict__ scTg,
                                                   short* __restrict__ Sch) {
  const int tid = threadIdx.x;
  const int wv = tid >> 6, lane = tid & 63, quad = lane >> 4, lq = lane & 15;
  const int b = blockIdx.x >> 5, ch = blockIdx.x & 31;
  const size_t gb = (size_t)blockIdx.x * 4096;
  __shared__ short sE[64 * 64];     // rows i, cols d (swizzled)
  __shared__ short sWT[64 * 64];    // rows e, cols d (swizzled) = w^T
  __shared__ short sF[64 * 64];     // rows i, cols e (swizzled)
  __shared__ short sFT[64 * 64];    // rows d, cols i (swizzled) = F^T
  __shared__ short sGT[2][64 * 64]; // rows h(local), cols i (swizzled), double-buffered

  // gather E rows -> sE + Eg;  stage w^T
  {
    const int i = tid >> 2, seg = tid & 3;
    const int idx = x[b * Ll + ch * Cc + i];
    const float4* aer = (const float4*)(ae + (size_t)idx * Dd) + seg * 4;
    float4 ev[4];
#pragma unroll
    for (int q = 0; q < 4; ++q) ev[q] = aer[q];
    uint4 pA, pB;
    pA.x = pack2(ev[0].x, ev[0].y); pA.y = pack2(ev[0].z, ev[0].w);
    pA.z = pack2(ev[1].x, ev[1].y); pA.w = pack2(ev[1].z, ev[1].w);
    pB.x = pack2(ev[2].x, ev[2].y); pB.y = pack2(ev[2].z, ev[2].w);
    pB.z = pack2(ev[3].x, ev[3].y); pB.w = pack2(ev[3].z, ev[3].w);
    *(uint4*)&sE[i * 64 + (((2 * seg) ^ (i & 7)) << 3)] = pA;
    *(uint4*)&sE[i * 64 + (((2 * seg + 1) ^ (i & 7)) << 3)] = pB;
    *(uint4*)(Eg + gb + i * 64 + seg * 16) = pA;
    *(uint4*)(Eg + gb + i * 64 + seg * 16 + 8) = pB;
    const float4* wr = (const float4*)w;
#pragma unroll
    for (int q = 0; q < 4; ++q) {
      const int fl = q * 256 + tid;
      const int d = fl >> 4, es = (fl & 15) * 4;
      const float4 v = wr[fl];
      const float vv[4] = {v.x, v.y, v.z, v.w};
#pragma unroll
      for (int c = 0; c < 4; ++c) {
        const int e = es + c;
        sWT[e * 64 + (((d >> 3) ^ (e & 7)) << 3) + (d & 7)] = f2bf(vv[c]);
      }
    }
  }
  __syncthreads();

  const int rm = wv * 16 + lq;
  bf16x8 aE[2], aW[2];
#pragma unroll
  for (int ks = 0; ks < 2; ++ks) {
    const int blk = ((ks * 4 + quad) ^ (rm & 7)) << 3;
    aE[ks] = *(const bf16x8*)&sE[rm * 64 + blk];
    aW[ks] = *(const bf16x8*)&sWT[rm * 64 + blk];
  }

  // F[i][e] -> sF ;  F^T[d][i] -> sFT (both swizzled LDS)
#pragma unroll
  for (int nt = 0; nt < 4; ++nt) {
    const int rn = nt * 16 + lq;
    f32x4 accF = {}, accT = {};
#pragma unroll
    for (int ks = 0; ks < 2; ++ks) {
      const int blk = ((ks * 4 + quad) ^ (rn & 7)) << 3;
      const bf16x8 bW = *(const bf16x8*)&sWT[rn * 64 + blk];
      const bf16x8 bE = *(const bf16x8*)&sE[rn * 64 + blk];
      accF = __builtin_amdgcn_mfma_f32_16x16x32_bf16(aE[ks], bW, accF, 0, 0, 0);
      accT = __builtin_amdgcn_mfma_f32_16x16x32_bf16(aW[ks], bE, accT, 0, 0, 0);
    }
#pragma unroll
    for (int r = 0; r < 4; ++r) {
      const int i = wv * 16 + quad * 4 + r;   // m of accF
      const int e = nt * 16 + lq;
      sF[i * 64 + (((e >> 3) ^ (i & 7)) << 3) + (e & 7)] = f2bf(accF[r]);
      const int d2 = wv * 16 + quad * 4 + r;  // m of accT (row d of F^T)
      const int i2 = nt * 16 + lq;
      sFT[d2 * 64 + (((i2 >> 3) ^ (d2 & 7)) << 3) + (i2 & 7)] = f2bf(accT[r]);
    }
  }
  __syncthreads();

  // prefetch G^T pass 0 while scT computes
  const int ip = tid & 31, hg = tid >> 5;
  float4 rGa[2], rGb[2];
  auto load_G = [&](int p) {
    const float* xr = bx + ((size_t)(b * Ll) + ch * Cc + 2 * ip) * Hh + p * 64 + hg * 8;
    rGa[0] = *(const float4*)(xr);
    rGa[1] = *(const float4*)(xr + 4);
    rGb[0] = *(const float4*)(xr + Hh);
    rGb[1] = *(const float4*)(xr + Hh + 4);
  };
  load_G(0);

  // sc[j][i] = sum_e E[j][e] F[i][e], strict mask i<j -> scTg rows j (linear frag layout)
#pragma unroll
  for (int nt = 0; nt < 4; ++nt) {
    const int rn = nt * 16 + lq;
    f32x4 acc = {};
#pragma unroll
    for (int ks = 0; ks < 2; ++ks) {
      const int blk = ((ks * 4 + quad) ^ (rn & 7)) << 3;
      const bf16x8 bF = *(const bf16x8*)&sF[rn * 64 + blk];
      acc = __builtin_amdgcn_mfma_f32_16x16x32_bf16(aE[ks], bF, acc, 0, 0, 0);
    }
#pragma unroll
    for (int r = 0; r < 4; ++r) {
      const int j = wv * 16 + quad * 4 + r;
      const int i = nt * 16 + lq;
      scTg[gb + j * 64 + i] = f2bf(i < j ? acc[r] : 0.f);
    }
  }

  // F^T B-fragments (rows d, k = i), read once
  bf16x8 bFT[4][2];
#pragma unroll
  for (int nt = 0; nt < 4; ++nt) {
    const int rn = nt * 16 + lq;
#pragma unroll
    for (int ks = 0; ks < 2; ++ks) {
      const int blk = ((ks * 4 + quad) ^ (rn & 7)) << 3;
      bFT[nt][ks] = *(const bf16x8*)&sFT[rn * 64 + blk];
    }
  }

  // 12 passes over h: Schunk[h,d] = mfma(G^T rows h, F^T rows d)
  short* So = Sch + (size_t)blockIdx.x * (Hh * Dd);
#pragma unroll 2
  for (int p = 0; p < NPASS; ++p) {
    const int cur = p & 1;
    {
      const float s0 = (float)(ch * Cc + 2 * ip + 1), s1 = (float)(ch * Cc + 2 * ip + 2);
      const float A[8] = {rGa[0].x, rGa[0].y, rGa[0].z, rGa[0].w,
                          rGa[1].x, rGa[1].y, rGa[1].z, rGa[1].w};
      const float Bv[8] = {rGb[0].x, rGb[0].y, rGb[0].z, rGb[0].w,
                           rGb[1].x, rGb[1].y, rGb[1].z, rGb[1].w};
#pragma unroll
      for (int e = 0; e < 8; ++e) {
        const int hl = hg * 8 + e;
        const int sa = hl * 64 + (((ip >> 2) ^ (hl & 7)) << 3) + 2 * (ip & 3);
        *(unsigned*)&sGT[cur][sa] = pack2(A[e] * s0, Bv[e] * s1);
      }
    }
    if (p + 1 < NPASS) load_G(p + 1);
    sync_lds();
    bf16x8 aG[2];
#pragma unroll
    for (int ks = 0; ks < 2; ++ks) {
      const int blk = ((ks * 4 + quad) ^ (rm & 7)) << 3;
      aG[ks] = *(const bf16x8*)&sGT[cur][rm * 64 + blk];
    }
#pragma unroll
    for (int nt = 0; nt < 4; ++nt) {
      f32x4 acc = {};
#pragma unroll
      for (int ks = 0; ks < 2; ++ks)
        acc = __builtin_amdgcn_mfma_f32_16x16x32_bf16(aG[ks], bFT[nt][ks], acc, 0, 0, 0);
#pragma unroll
      for (int r = 0; r < 4; ++r) {
        const int h = p * 64 + wv * 16 + quad * 4 + r;
        So[h * 64 + nt * 16 + lq] = f2bf(acc[r]);
      }
    }
  }
}

// ---------------- Prefix: in-place EXCLUSIVE prefix over 32 chunk planes per b ----------------
__global__ __launch_bounds__(256) void prefix_kernel(short* __restrict__ Sch) {
  const int b = blockIdx.x / 48;                        // 48 blocks per b
  const int v = (blockIdx.x % 48) * 256 + threadIdx.x;  // uint2 index in plane [0,12288)
  uint2* base = (uint2*)(Sch + (size_t)b * NCH * (Hh * Dd)) + v;
  const int stride = Hh * Dd / 4;  // uint2 per plane
  uint2 va[NCH];
#pragma unroll
  for (int s = 0; s < NCH; ++s) va[s] = base[s * stride];  // load all first (no RW hazard)
  float4 acc = {0.f, 0.f, 0.f, 0.f};
#pragma unroll
  for (int s = 0; s < NCH; ++s) {
    uint2 o;
    o.x = pack2(acc.x, acc.y);
    o.y = pack2(acc.z, acc.w);
    base[s * stride] = o;  // exclusive prefix (plane 0 = zeros)
    acc.x += bf2f((unsigned short)(va[s].x & 0xffffu));
    acc.y += bf2f((unsigned short)(va[s].x >> 16));
    acc.z += bf2f((unsigned short)(va[s].y & 0xffffu));
    acc.w += bf2f((unsigned short)(va[s].y >> 16));
  }
}

// ---------------- Scan: fully parallel, per (tile, b, ch) — no carry, no loop ----------------
// out[j,h] = bx[j,h] + (1/(j+1)) * [ sum_{i<j in ch} sc[j,i]*G[i,h]  +  sum_d E[j,d]*Sprefix[h,d] ]
__global__ __launch_bounds__(256) void scan_kernel(const float* __restrict__ bx,
                                                   const short* __restrict__ Eg,
                                                   const short* __restrict__ scTg,
                                                   const short* __restrict__ STg,
                                                   float* __restrict__ out) {
  const int s = blockIdx.x;             // [0, 12*512): tile-major -> bc%8 fixes XCD for all 12 tiles
  const int tile = s >> 9;              // s / 512
  const int bc = s & 511;               // (b,ch)
  const int b = bc >> 5, ch = bc & 31;
  const int tid = threadIdx.x;
  const int w = tid >> 6, lane = tid & 63, quad = lane >> 4, lq = lane & 15;
  const int ip = tid & 31, hg = tid >> 5;
  const int rj = w * 16 + lq;

  __shared__ short sGT[64 * 64];  // G^T rows h(local), cols i (swizzled)

  // issue all global loads up front
  float4 rGa[2], rGb[2];
  {
    const float* xr = bx + ((size_t)(b * Ll) + ch * Cc + 2 * ip) * Hh + tile * HC + hg * 8;
    rGa[0] = *(const float4*)(xr);
    rGa[1] = *(const float4*)(xr + 4);
    rGb[0] = *(const float4*)(xr + Hh);
    rGb[1] = *(const float4*)(xr + Hh + 4);
  }
  bf16x8 aC1[2], aC2[2];  // scT rows j (k=i), E rows j (k=d)
  {
    const size_t tb = (size_t)bc * 4096;
#pragma unroll
    for (int ks = 0; ks < 2; ++ks) {
      const int o = rj * 64 + (ks * 4 + quad) * 8;
      aC1[ks] = *(const bf16x8*)(scTg + tb + o);
      aC2[ks] = *(const bf16x8*)(Eg + tb + o);
    }
  }
  bf16x8 stF[4][2];  // Sprefix rows h (k=d), fragment-ready linear layout
  {
    const short* Sp = STg + (size_t)bc * (Hh * Dd);
#pragma unroll
    for (int ht = 0; ht < 4; ++ht) {
      const int h = tile * HC + ht * 16 + lq;
#pragma unroll
      for (int ks = 0; ks < 2; ++ks)
        stF[ht][ks] = *(const bf16x8*)(Sp + h * 64 + (ks * 4 + quad) * 8);
    }
  }

  // stage G^T (scaled bx, h x i) into LDS
  {
    const float s0 = (float)(ch * Cc + 2 * ip + 1), s1 = (float)(ch * Cc + 2 * ip + 2);
    const float A[8] = {rGa[0].x, rGa[0].y, rGa[0].z, rGa[0].w,
                        rGa[1].x, rGa[1].y, rGa[1].z, rGa[1].w};
    const float Bv[8] = {rGb[0].x, rGb[0].y, rGb[0].z, rGb[0].w,
                         rGb[1].x, rGb[1].y, rGb[1].z, rGb[1].w};
#pragma unroll
    for (int e = 0; e < 8; ++e) {
      const int hl = hg * 8 + e;
      const int sa = hl * 64 + (((ip >> 2) ^ (hl & 7)) << 3) + 2 * (ip & 3);
      *(unsigned*)&sGT[sa] = pack2(A[e] * s0, Bv[e] * s1);
    }
  }
  sync_lds();

#pragma unroll
  for (int ht = 0; ht < 4; ++ht) {
    const int rh = ht * 16 + lq;
    f32x4 accO = {};
#pragma unroll
    for (int ks = 0; ks < 2; ++ks) {
      const int blk = ((ks * 4 + quad) ^ (rh & 7)) << 3;
      const bf16x8 gv = *(const bf16x8*)&sGT[rh * 64 + blk];
      accO = __builtin_amdgcn_mfma_f32_16x16x32_bf16(aC1[ks], gv, accO, 0, 0, 0);
      accO = __builtin_amdgcn_mfma_f32_16x16x32_bf16(aC2[ks], stF[ht][ks], accO, 0, 0, 0);
    }
#pragma unroll
    for (int r = 0; r < 4; ++r) {
      const int gj = ch * Cc + w * 16 + quad * 4 + r;
      const size_t off = ((size_t)(b * Ll) + gj) * Hh + tile * HC + ht * 16 + lq;
      out[off] = bx[off] + accO[r] * (1.0f / (float)(gj + 1));
    }
  }
}

extern "C" void kernel_launch(void* const* d_in, const int* in_sizes, int n_in,
                              void* d_out, int out_size, void* d_ws, size_t ws_size,
                              hipStream_t stream) {
  (void)in_sizes; (void)n_in; (void)out_size; (void)ws_size;
  const float* bx = (const float*)d_in[0];
  const int* x = (const int*)d_in[1];
  const float* ae = (const float*)d_in[2];
  const float* w = (const float*)d_in[3];
  float* out = (float*)d_out;
  short* Eg = (short*)d_ws;                        // 512*4096 bf16 = 4 MB
  short* scTg = Eg + (size_t)512 * 4096;           // 4 MB
  short* Sch = scTg + (size_t)512 * 4096;          // 512*768*64 bf16 = 50.3 MB (in-place -> STg)

  prep_kernel<<<Bb * NCH, 256, 0, stream>>>(x, ae, w, bx, Eg, scTg, Sch);
  prefix_kernel<<<Bb * 48, 256, 0, stream>>>(Sch);
  scan_kernel<<<NT * Bb * NCH, 256, 0, stream>>>(bx, Eg, scTg, Sch, out);
}

// Round 4
// 263.884 us; speedup vs baseline: 1.1189x; 1.0078x over previous
//
#include <hip/hip_runtime.h>

#define Bb 16
#define Ll 2048
#define Hh 768
#define Dd 64
#define Cc 64
#define HC 64             // h-tile width for scan (256 B rows -> full-line stores)
#define NT (Hh / HC)      // 12 h-tiles
#define NCH (Ll / Cc)     // 32 chunks
#define NG 6              // prep phase-2: 6 groups x 128 h

typedef __attribute__((ext_vector_type(8))) short bf16x8;
typedef __attribute__((ext_vector_type(4))) float f32x4;

__device__ __forceinline__ short f2bf(float f) {
  union { float f; unsigned u; } c;
  c.f = f;
  unsigned r = (c.u + 0x7FFFu + ((c.u >> 16) & 1u)) >> 16;
  return (short)r;
}
__device__ __forceinline__ unsigned pack2(float a, float b) {
  return (unsigned)(unsigned short)f2bf(a) | ((unsigned)(unsigned short)f2bf(b) << 16);
}
__device__ __forceinline__ float bf2f(unsigned short s) {
  union { unsigned u; float f; } c;
  c.u = ((unsigned)s) << 16;
  return c.f;
}

// CK-style barrier: waits LDS ops only; global loads stay in flight.
__device__ __forceinline__ void sync_lds() {
  asm volatile("s_waitcnt lgkmcnt(0)\n\ts_barrier" ::: "memory");
}

// ---------------- Prep (512 thr): per (b,chunk) -> E, scT (frag layout) + Schunk[768][64] ----------------
// Schunk[h,d] = sum_{i in chunk} (global_i+1)*bx[i,h]*F[i,d]
__global__ __launch_bounds__(512) void prep_kernel(const int* __restrict__ x,
                                                   const float* __restrict__ ae,
                                                   const float* __restrict__ w,
                                                   const float* __restrict__ bx,
                                                   short* __restrict__ Eg,
                                                   short* __restrict__ scTg,
                                                   short* __restrict__ Sch) {
  const int tid = threadIdx.x;
  const int wv = tid >> 6, lane = tid & 63, quad = lane >> 4, lq = lane & 15;
  const int mt = wv >> 1, np = wv & 1;   // 8 waves: m-tile 0..3, nt-pair 0..1
  const int b = blockIdx.x >> 5, ch = blockIdx.x & 31;
  const size_t gb = (size_t)blockIdx.x * 4096;
  // 32 KB aliased pool: phase1 = sE|sWT|sF|sFT; phase2 = two 16 KB G^T buffers
  __shared__ short pool[4 * 4096];
  short* sE  = pool;
  short* sWT = pool + 4096;
  short* sF  = pool + 8192;
  short* sFT = pool + 12288;

  // ---- Phase 1a: gather E rows -> sE + Eg; stage w^T ----
  {
    const int i = tid >> 3, seg = tid & 7;
    const int idx = x[b * Ll + ch * Cc + i];
    const float4* aer = (const float4*)(ae + (size_t)idx * Dd) + seg * 2;
    const float4 a0 = aer[0], a1 = aer[1];
    uint4 p;
    p.x = pack2(a0.x, a0.y); p.y = pack2(a0.z, a0.w);
    p.z = pack2(a1.x, a1.y); p.w = pack2(a1.z, a1.w);
    *(uint4*)&sE[i * 64 + ((seg ^ (i & 7)) << 3)] = p;
    *(uint4*)(Eg + gb + i * 64 + seg * 8) = p;
    const float4* wr = (const float4*)w;
#pragma unroll
    for (int q = 0; q < 2; ++q) {
      const int fl = q * 512 + tid;
      const int d = fl >> 4, es = (fl & 15) * 4;
      const float4 v = wr[fl];
      const float vv[4] = {v.x, v.y, v.z, v.w};
#pragma unroll
      for (int c = 0; c < 4; ++c) {
        const int e = es + c;
        sWT[e * 64 + (((d >> 3) ^ (e & 7)) << 3) + (d & 7)] = f2bf(vv[c]);
      }
    }
  }
  __syncthreads();

  const int rm = mt * 16 + lq;
  bf16x8 aE[2], aW[2];
#pragma unroll
  for (int ks = 0; ks < 2; ++ks) {
    const int blk = ((ks * 4 + quad) ^ (rm & 7)) << 3;
    aE[ks] = *(const bf16x8*)&sE[rm * 64 + blk];
    aW[ks] = *(const bf16x8*)&sWT[rm * 64 + blk];
  }

  // ---- Phase 1b: F[i][e] -> sF ; F^T[d][i] -> sFT (each wave: its m-tile x 2 n-tiles) ----
#pragma unroll
  for (int t = 0; t < 2; ++t) {
    const int nt = np * 2 + t;
    const int rn = nt * 16 + lq;
    f32x4 accF = {}, accT = {};
#pragma unroll
    for (int ks = 0; ks < 2; ++ks) {
      const int blk = ((ks * 4 + quad) ^ (rn & 7)) << 3;
      const bf16x8 bW = *(const bf16x8*)&sWT[rn * 64 + blk];
      const bf16x8 bE = *(const bf16x8*)&sE[rn * 64 + blk];
      accF = __builtin_amdgcn_mfma_f32_16x16x32_bf16(aE[ks], bW, accF, 0, 0, 0);
      accT = __builtin_amdgcn_mfma_f32_16x16x32_bf16(aW[ks], bE, accT, 0, 0, 0);
    }
#pragma unroll
    for (int r = 0; r < 4; ++r) {
      const int i = mt * 16 + quad * 4 + r;
      const int e = nt * 16 + lq;
      sF[i * 64 + (((e >> 3) ^ (i & 7)) << 3) + (e & 7)] = f2bf(accF[r]);
      const int d2 = mt * 16 + quad * 4 + r;
      const int i2 = nt * 16 + lq;
      sFT[d2 * 64 + (((i2 >> 3) ^ (d2 & 7)) << 3) + (i2 & 7)] = f2bf(accT[r]);
    }
  }
  __syncthreads();   // last reads of sE/sWT happen above; G-buffer A reuse is safe after this

  // prefetch G group 0 while scT computes
  const int ip = tid & 31, hg = tid >> 5;   // ip: i-pair 0..31; hg: 0..15 -> 8 h each (128 h/group)
  float4 rGa[2], rGb[2];
  auto load_G = [&](int g) {
    const float* xr = bx + ((size_t)(b * Ll) + ch * Cc + 2 * ip) * Hh + g * 128 + hg * 8;
    rGa[0] = *(const float4*)(xr);
    rGa[1] = *(const float4*)(xr + 4);
    rGb[0] = *(const float4*)(xr + Hh);
    rGb[1] = *(const float4*)(xr + Hh + 4);
  };
  load_G(0);

  // ---- Phase 1c: sc[j][i] = sum_e E[j][e] F[i][e], strict mask -> scTg (frag layout) ----
#pragma unroll
  for (int t = 0; t < 2; ++t) {
    const int nt = np * 2 + t;
    const int rn = nt * 16 + lq;
    f32x4 acc = {};
#pragma unroll
    for (int ks = 0; ks < 2; ++ks) {
      const int blk = ((ks * 4 + quad) ^ (rn & 7)) << 3;
      const bf16x8 bF = *(const bf16x8*)&sF[rn * 64 + blk];
      acc = __builtin_amdgcn_mfma_f32_16x16x32_bf16(aE[ks], bF, acc, 0, 0, 0);
    }
#pragma unroll
    for (int r = 0; r < 4; ++r) {
      const int j = mt * 16 + quad * 4 + r;
      const int i = nt * 16 + lq;
      scTg[gb + j * 64 + i] = f2bf(i < j ? acc[r] : 0.f);
    }
  }

  // F^T B-fragments (rows d, k = i) — every wave needs all 4 d-tiles
  bf16x8 bFT[4][2];
#pragma unroll
  for (int nt = 0; nt < 4; ++nt) {
    const int rn = nt * 16 + lq;
#pragma unroll
    for (int ks = 0; ks < 2; ++ks) {
      const int blk = ((ks * 4 + quad) ^ (rn & 7)) << 3;
      bFT[nt][ks] = *(const bf16x8*)&sFT[rn * 64 + blk];
    }
  }

  // ---- Phase 2: 6 groups x 128 h: Schunk[h,d] = mfma(G^T rows h, F^T rows d) ----
  // G buffers alias pool: buf0 = pool[0:8192] (sE+sWT), buf1 = pool[8192:16384] (sF+sFT).
  // buf1's first write (g=1 staging) is ordered after all sF/sFT reads by g=0's sync_lds.
  short* So = Sch + (size_t)blockIdx.x * (Hh * Dd);
#pragma unroll 2
  for (int g = 0; g < NG; ++g) {
    short* gbuf = pool + (g & 1) * 8192;
    {
      const float s0 = (float)(ch * Cc + 2 * ip + 1), s1 = (float)(ch * Cc + 2 * ip + 2);
      const float A[8] = {rGa[0].x, rGa[0].y, rGa[0].z, rGa[0].w,
                          rGa[1].x, rGa[1].y, rGa[1].z, rGa[1].w};
      const float Bv[8] = {rGb[0].x, rGb[0].y, rGb[0].z, rGb[0].w,
                           rGb[1].x, rGb[1].y, rGb[1].z, rGb[1].w};
#pragma unroll
      for (int e = 0; e < 8; ++e) {
        const int hl = hg * 8 + e;   // 0..127
        const int sa = hl * 64 + (((ip >> 2) ^ (hl & 7)) << 3) + 2 * (ip & 3);
        *(unsigned*)&gbuf[sa] = pack2(A[e] * s0, Bv[e] * s1);
      }
    }
    if (g + 1 < NG) load_G(g + 1);
    sync_lds();
    const int rh = wv * 16 + lq;   // this wave's 16 h-rows within the 128-row buffer
    bf16x8 aG[2];
#pragma unroll
    for (int ks = 0; ks < 2; ++ks) {
      const int blk = ((ks * 4 + quad) ^ (rh & 7)) << 3;
      aG[ks] = *(const bf16x8*)&gbuf[rh * 64 + blk];
    }
#pragma unroll
    for (int nt = 0; nt < 4; ++nt) {
      f32x4 acc = {};
#pragma unroll
      for (int ks = 0; ks < 2; ++ks)
        acc = __builtin_amdgcn_mfma_f32_16x16x32_bf16(aG[ks], bFT[nt][ks], acc, 0, 0, 0);
#pragma unroll
      for (int r = 0; r < 4; ++r) {
        const int h = g * 128 + wv * 16 + quad * 4 + r;
        So[h * 64 + nt * 16 + lq] = f2bf(acc[r]);
      }
    }
  }
}

// ---------------- Prefix: in-place EXCLUSIVE prefix over 32 chunk planes per b ----------------
__global__ __launch_bounds__(256) void prefix_kernel(short* __restrict__ Sch) {
  const int b = blockIdx.x / 48;                        // 48 blocks per b
  const int v = (blockIdx.x % 48) * 256 + threadIdx.x;  // uint2 index in plane [0,12288)
  uint2* base = (uint2*)(Sch + (size_t)b * NCH * (Hh * Dd)) + v;
  const int stride = Hh * Dd / 4;  // uint2 per plane
  uint2 va[NCH];
#pragma unroll
  for (int s = 0; s < NCH; ++s) va[s] = base[s * stride];  // load all first (no RW hazard)
  float4 acc = {0.f, 0.f, 0.f, 0.f};
#pragma unroll
  for (int s = 0; s < NCH; ++s) {
    uint2 o;
    o.x = pack2(acc.x, acc.y);
    o.y = pack2(acc.z, acc.w);
    base[s * stride] = o;  // exclusive prefix (plane 0 = zeros)
    acc.x += bf2f((unsigned short)(va[s].x & 0xffffu));
    acc.y += bf2f((unsigned short)(va[s].x >> 16));
    acc.z += bf2f((unsigned short)(va[s].y & 0xffffu));
    acc.w += bf2f((unsigned short)(va[s].y >> 16));
  }
}

// ---------------- Scan: fully parallel, per (tile, b, ch) — no carry, no loop ----------------
// out[j,h] = bx[j,h] + (1/(j+1)) * [ sum_{i<j in ch} sc[j,i]*G[i,h]  +  sum_d E[j,d]*Sprefix[h,d] ]
__global__ __launch_bounds__(256) void scan_kernel(const float* __restrict__ bx,
                                                   const short* __restrict__ Eg,
                                                   const short* __restrict__ scTg,
                                                   const short* __restrict__ STg,
                                                   float* __restrict__ out) {
  const int s = blockIdx.x;             // [0, 12*512): tile-major -> bc%8 fixes XCD for all 12 tiles
  const int tile = s >> 9;              // s / 512
  const int bc = s & 511;               // (b,ch)
  const int b = bc >> 5, ch = bc & 31;
  const int tid = threadIdx.x;
  const int w = tid >> 6, lane = tid & 63, quad = lane >> 4, lq = lane & 15;
  const int ip = tid & 31, hg = tid >> 5;
  const int rj = w * 16 + lq;

  __shared__ short sGT[64 * 64];  // G^T rows h(local), cols i (swizzled)

  // issue all global loads up front
  float4 rGa[2], rGb[2];
  {
    const float* xr = bx + ((size_t)(b * Ll) + ch * Cc + 2 * ip) * Hh + tile * HC + hg * 8;
    rGa[0] = *(const float4*)(xr);
    rGa[1] = *(const float4*)(xr + 4);
    rGb[0] = *(const float4*)(xr + Hh);
    rGb[1] = *(const float4*)(xr + Hh + 4);
  }
  bf16x8 aC1[2], aC2[2];  // scT rows j (k=i), E rows j (k=d)
  {
    const size_t tb = (size_t)bc * 4096;
#pragma unroll
    for (int ks = 0; ks < 2; ++ks) {
      const int o = rj * 64 + (ks * 4 + quad) * 8;
      aC1[ks] = *(const bf16x8*)(scTg + tb + o);
      aC2[ks] = *(const bf16x8*)(Eg + tb + o);
    }
  }
  bf16x8 stF[4][2];  // Sprefix rows h (k=d), fragment-ready linear layout
  {
    const short* Sp = STg + (size_t)bc * (Hh * Dd);
#pragma unroll
    for (int ht = 0; ht < 4; ++ht) {
      const int h = tile * HC + ht * 16 + lq;
#pragma unroll
      for (int ks = 0; ks < 2; ++ks)
        stF[ht][ks] = *(const bf16x8*)(Sp + h * 64 + (ks * 4 + quad) * 8);
    }
  }

  // stage G^T (scaled bx, h x i) into LDS
  {
    const float s0 = (float)(ch * Cc + 2 * ip + 1), s1 = (float)(ch * Cc + 2 * ip + 2);
    const float A[8] = {rGa[0].x, rGa[0].y, rGa[0].z, rGa[0].w,
                        rGa[1].x, rGa[1].y, rGa[1].z, rGa[1].w};
    const float Bv[8] = {rGb[0].x, rGb[0].y, rGb[0].z, rGb[0].w,
                         rGb[1].x, rGb[1].y, rGb[1].z, rGb[1].w};
#pragma unroll
    for (int e = 0; e < 8; ++e) {
      const int hl = hg * 8 + e;
      const int sa = hl * 64 + (((ip >> 2) ^ (hl & 7)) << 3) + 2 * (ip & 3);
      *(unsigned*)&sGT[sa] = pack2(A[e] * s0, Bv[e] * s1);
    }
  }
  sync_lds();

#pragma unroll
  for (int ht = 0; ht < 4; ++ht) {
    const int rh = ht * 16 + lq;
    f32x4 accO = {};
#pragma unroll
    for (int ks = 0; ks < 2; ++ks) {
      const int blk = ((ks * 4 + quad) ^ (rh & 7)) << 3;
      const bf16x8 gv = *(const bf16x8*)&sGT[rh * 64 + blk];
      accO = __builtin_amdgcn_mfma_f32_16x16x32_bf16(aC1[ks], gv, accO, 0, 0, 0);
      accO = __builtin_amdgcn_mfma_f32_16x16x32_bf16(aC2[ks], stF[ht][ks], accO, 0, 0, 0);
    }
#pragma unroll
    for (int r = 0; r < 4; ++r) {
      const int gj = ch * Cc + w * 16 + quad * 4 + r;
      const size_t off = ((size_t)(b * Ll) + gj) * Hh + tile * HC + ht * 16 + lq;
      out[off] = bx[off] + accO[r] * (1.0f / (float)(gj + 1));
    }
  }
}

extern "C" void kernel_launch(void* const* d_in, const int* in_sizes, int n_in,
                              void* d_out, int out_size, void* d_ws, size_t ws_size,
                              hipStream_t stream) {
  (void)in_sizes; (void)n_in; (void)out_size; (void)ws_size;
  const float* bx = (const float*)d_in[0];
  const int* x = (const int*)d_in[1];
  const float* ae = (const float*)d_in[2];
  const float* w = (const float*)d_in[3];
  float* out = (float*)d_out;
  short* Eg = (short*)d_ws;                        // 512*4096 bf16 = 4 MB
  short* scTg = Eg + (size_t)512 * 4096;           // 4 MB
  short* Sch = scTg + (size_t)512 * 4096;          // 512*768*64 bf16 = 50.3 MB (in-place -> STg)

  prep_kernel<<<Bb * NCH, 512, 0, stream>>>(x, ae, w, bx, Eg, scTg, Sch);
  prefix_kernel<<<Bb * 48, 256, 0, stream>>>(Sch);
  scan_kernel<<<NT * Bb * NCH, 256, 0, stream>>>(bx, Eg, scTg, Sch, out);
}

// Round 5
// 259.925 us; speedup vs baseline: 1.1359x; 1.0152x over previous
//
#include <hip/hip_runtime.h>

#define Bb 16
#define Ll 2048
#define Hh 768
#define Dd 64
#define Cc 64
#define HC 64             // h-tile width for scan (256 B rows -> full-line stores)
#define NT (Hh / HC)      // 12 h-tiles
#define NCH (Ll / Cc)     // 32 chunks
#define NG 6              // prep phase-2: 6 groups x 128 h
#define TG 4              // scan: tiles per block
#define NTG (NT / TG)     // 3 tile-groups

typedef __attribute__((ext_vector_type(8))) short bf16x8;
typedef __attribute__((ext_vector_type(4))) float f32x4;

__device__ __forceinline__ short f2bf(float f) {
  union { float f; unsigned u; } c;
  c.f = f;
  unsigned r = (c.u + 0x7FFFu + ((c.u >> 16) & 1u)) >> 16;
  return (short)r;
}
__device__ __forceinline__ unsigned pack2(float a, float b) {
  return (unsigned)(unsigned short)f2bf(a) | ((unsigned)(unsigned short)f2bf(b) << 16);
}
__device__ __forceinline__ float bf2f(unsigned short s) {
  union { unsigned u; float f; } c;
  c.u = ((unsigned)s) << 16;
  return c.f;
}

// CK-style barrier: waits LDS ops only; global loads stay in flight.
__device__ __forceinline__ void sync_lds() {
  asm volatile("s_waitcnt lgkmcnt(0)\n\ts_barrier" ::: "memory");
}

// ---------------- Prep (512 thr): per (b,chunk) -> E, scT (frag layout) + Schunk[768][64] ----------------
// Schunk[h,d] = sum_{i in chunk} (global_i+1)*bx[i,h]*F[i,d]
__global__ __launch_bounds__(512) void prep_kernel(const int* __restrict__ x,
                                                   const float* __restrict__ ae,
                                                   const float* __restrict__ w,
                                                   const float* __restrict__ bx,
                                                   short* __restrict__ Eg,
                                                   short* __restrict__ scTg,
                                                   short* __restrict__ Sch) {
  const int tid = threadIdx.x;
  const int wv = tid >> 6, lane = tid & 63, quad = lane >> 4, lq = lane & 15;
  const int mt = wv >> 1, np = wv & 1;   // 8 waves: m-tile 0..3, nt-pair 0..1
  const int b = blockIdx.x >> 5, ch = blockIdx.x & 31;
  const size_t gb = (size_t)blockIdx.x * 4096;
  // 32 KB aliased pool: phase1 = sE|sWT|sF|sFT; phase2 = two 16 KB G^T buffers
  __shared__ short pool[4 * 4096];
  short* sE  = pool;
  short* sWT = pool + 4096;
  short* sF  = pool + 8192;
  short* sFT = pool + 12288;

  // ---- Phase 1a: gather E rows -> sE + Eg; stage w^T ----
  {
    const int i = tid >> 3, seg = tid & 7;
    const int idx = x[b * Ll + ch * Cc + i];
    const float4* aer = (const float4*)(ae + (size_t)idx * Dd) + seg * 2;
    const float4 a0 = aer[0], a1 = aer[1];
    uint4 p;
    p.x = pack2(a0.x, a0.y); p.y = pack2(a0.z, a0.w);
    p.z = pack2(a1.x, a1.y); p.w = pack2(a1.z, a1.w);
    *(uint4*)&sE[i * 64 + ((seg ^ (i & 7)) << 3)] = p;
    *(uint4*)(Eg + gb + i * 64 + seg * 8) = p;
    const float4* wr = (const float4*)w;
#pragma unroll
    for (int q = 0; q < 2; ++q) {
      const int fl = q * 512 + tid;
      const int d = fl >> 4, es = (fl & 15) * 4;
      const float4 v = wr[fl];
      const float vv[4] = {v.x, v.y, v.z, v.w};
#pragma unroll
      for (int c = 0; c < 4; ++c) {
        const int e = es + c;
        sWT[e * 64 + (((d >> 3) ^ (e & 7)) << 3) + (d & 7)] = f2bf(vv[c]);
      }
    }
  }
  __syncthreads();

  const int rm = mt * 16 + lq;
  bf16x8 aE[2], aW[2];
#pragma unroll
  for (int ks = 0; ks < 2; ++ks) {
    const int blk = ((ks * 4 + quad) ^ (rm & 7)) << 3;
    aE[ks] = *(const bf16x8*)&sE[rm * 64 + blk];
    aW[ks] = *(const bf16x8*)&sWT[rm * 64 + blk];
  }

  // ---- Phase 1b: F[i][e] -> sF ; F^T[d][i] -> sFT (each wave: its m-tile x 2 n-tiles) ----
#pragma unroll
  for (int t = 0; t < 2; ++t) {
    const int nt = np * 2 + t;
    const int rn = nt * 16 + lq;
    f32x4 accF = {}, accT = {};
#pragma unroll
    for (int ks = 0; ks < 2; ++ks) {
      const int blk = ((ks * 4 + quad) ^ (rn & 7)) << 3;
      const bf16x8 bW = *(const bf16x8*)&sWT[rn * 64 + blk];
      const bf16x8 bE = *(const bf16x8*)&sE[rn * 64 + blk];
      accF = __builtin_amdgcn_mfma_f32_16x16x32_bf16(aE[ks], bW, accF, 0, 0, 0);
      accT = __builtin_amdgcn_mfma_f32_16x16x32_bf16(aW[ks], bE, accT, 0, 0, 0);
    }
#pragma unroll
    for (int r = 0; r < 4; ++r) {
      const int i = mt * 16 + quad * 4 + r;
      const int e = nt * 16 + lq;
      sF[i * 64 + (((e >> 3) ^ (i & 7)) << 3) + (e & 7)] = f2bf(accF[r]);
      const int d2 = mt * 16 + quad * 4 + r;
      const int i2 = nt * 16 + lq;
      sFT[d2 * 64 + (((i2 >> 3) ^ (d2 & 7)) << 3) + (i2 & 7)] = f2bf(accT[r]);
    }
  }
  __syncthreads();   // last reads of sE/sWT happen above; G-buffer A reuse is safe after this

  // prefetch G group 0 while scT computes
  const int ip = tid & 31, hg = tid >> 5;   // ip: i-pair 0..31; hg: 0..15 -> 8 h each (128 h/group)
  float4 rGa[2], rGb[2];
  auto load_G = [&](int g) {
    const float* xr = bx + ((size_t)(b * Ll) + ch * Cc + 2 * ip) * Hh + g * 128 + hg * 8;
    rGa[0] = *(const float4*)(xr);
    rGa[1] = *(const float4*)(xr + 4);
    rGb[0] = *(const float4*)(xr + Hh);
    rGb[1] = *(const float4*)(xr + Hh + 4);
  };
  load_G(0);

  // ---- Phase 1c: sc[j][i] = sum_e E[j][e] F[i][e], strict mask -> scTg (frag layout) ----
#pragma unroll
  for (int t = 0; t < 2; ++t) {
    const int nt = np * 2 + t;
    const int rn = nt * 16 + lq;
    f32x4 acc = {};
#pragma unroll
    for (int ks = 0; ks < 2; ++ks) {
      const int blk = ((ks * 4 + quad) ^ (rn & 7)) << 3;
      const bf16x8 bF = *(const bf16x8*)&sF[rn * 64 + blk];
      acc = __builtin_amdgcn_mfma_f32_16x16x32_bf16(aE[ks], bF, acc, 0, 0, 0);
    }
#pragma unroll
    for (int r = 0; r < 4; ++r) {
      const int j = mt * 16 + quad * 4 + r;
      const int i = nt * 16 + lq;
      scTg[gb + j * 64 + i] = f2bf(i < j ? acc[r] : 0.f);
    }
  }

  // F^T B-fragments (rows d, k = i) — every wave needs all 4 d-tiles
  bf16x8 bFT[4][2];
#pragma unroll
  for (int nt = 0; nt < 4; ++nt) {
    const int rn = nt * 16 + lq;
#pragma unroll
    for (int ks = 0; ks < 2; ++ks) {
      const int blk = ((ks * 4 + quad) ^ (rn & 7)) << 3;
      bFT[nt][ks] = *(const bf16x8*)&sFT[rn * 64 + blk];
    }
  }

  // ---- Phase 2: 6 groups x 128 h: Schunk[h,d] = mfma(G^T rows h, F^T rows d) ----
  short* So = Sch + (size_t)blockIdx.x * (Hh * Dd);
#pragma unroll 2
  for (int g = 0; g < NG; ++g) {
    short* gbuf = pool + (g & 1) * 8192;
    {
      const float s0 = (float)(ch * Cc + 2 * ip + 1), s1 = (float)(ch * Cc + 2 * ip + 2);
      const float A[8] = {rGa[0].x, rGa[0].y, rGa[0].z, rGa[0].w,
                          rGa[1].x, rGa[1].y, rGa[1].z, rGa[1].w};
      const float Bv[8] = {rGb[0].x, rGb[0].y, rGb[0].z, rGb[0].w,
                           rGb[1].x, rGb[1].y, rGb[1].z, rGb[1].w};
#pragma unroll
      for (int e = 0; e < 8; ++e) {
        const int hl = hg * 8 + e;   // 0..127
        const int sa = hl * 64 + (((ip >> 2) ^ (hl & 7)) << 3) + 2 * (ip & 3);
        *(unsigned*)&gbuf[sa] = pack2(A[e] * s0, Bv[e] * s1);
      }
    }
    if (g + 1 < NG) load_G(g + 1);
    sync_lds();
    const int rh = wv * 16 + lq;   // this wave's 16 h-rows within the 128-row buffer
    bf16x8 aG[2];
#pragma unroll
    for (int ks = 0; ks < 2; ++ks) {
      const int blk = ((ks * 4 + quad) ^ (rh & 7)) << 3;
      aG[ks] = *(const bf16x8*)&gbuf[rh * 64 + blk];
    }
#pragma unroll
    for (int nt = 0; nt < 4; ++nt) {
      f32x4 acc = {};
#pragma unroll
      for (int ks = 0; ks < 2; ++ks)
        acc = __builtin_amdgcn_mfma_f32_16x16x32_bf16(aG[ks], bFT[nt][ks], acc, 0, 0, 0);
#pragma unroll
      for (int r = 0; r < 4; ++r) {
        const int h = g * 128 + wv * 16 + quad * 4 + r;
        So[h * 64 + nt * 16 + lq] = f2bf(acc[r]);
      }
    }
  }
}

// ---------------- Prefix: in-place EXCLUSIVE prefix over 32 chunk planes per b ----------------
__global__ __launch_bounds__(256) void prefix_kernel(short* __restrict__ Sch) {
  const int b = blockIdx.x / 48;                        // 48 blocks per b
  const int v = (blockIdx.x % 48) * 256 + threadIdx.x;  // uint2 index in plane [0,12288)
  uint2* base = (uint2*)(Sch + (size_t)b * NCH * (Hh * Dd)) + v;
  const int stride = Hh * Dd / 4;  // uint2 per plane
  uint2 va[NCH];
#pragma unroll
  for (int s = 0; s < NCH; ++s) va[s] = base[s * stride];  // load all first (no RW hazard)
  float4 acc = {0.f, 0.f, 0.f, 0.f};
#pragma unroll
  for (int s = 0; s < NCH; ++s) {
    uint2 o;
    o.x = pack2(acc.x, acc.y);
    o.y = pack2(acc.z, acc.w);
    base[s * stride] = o;  // exclusive prefix (plane 0 = zeros)
    acc.x += bf2f((unsigned short)(va[s].x & 0xffffu));
    acc.y += bf2f((unsigned short)(va[s].x >> 16));
    acc.z += bf2f((unsigned short)(va[s].y & 0xffffu));
    acc.w += bf2f((unsigned short)(va[s].y >> 16));
  }
}

// ---------------- Scan: per (tile-group, b, ch) — 4 pipelined h-tiles sharing frags ----------------
// out[j,h] = bx[j,h] + (1/(j+1)) * [ sum_{i<j in ch} sc[j,i]*G[i,h]  +  sum_d E[j,d]*Sprefix[h,d] ]
__global__ __launch_bounds__(256) void scan_kernel(const float* __restrict__ bx,
                                                   const short* __restrict__ Eg,
                                                   const short* __restrict__ scTg,
                                                   const short* __restrict__ STg,
                                                   float* __restrict__ out) {
  const int s = blockIdx.x;             // [0, 3*512): bc%8 fixes XCD for all 3 tile-groups of a bc
  const int tg = s >> 9;                // tile-group 0..2
  const int bc = s & 511;               // (b,ch)
  const int b = bc >> 5, ch = bc & 31;
  const int tid = threadIdx.x;
  const int w = tid >> 6, lane = tid & 63, quad = lane >> 4, lq = lane & 15;
  const int ip = tid & 31, hg = tid >> 5;
  const int rj = w * 16 + lq;

  __shared__ short sGT[2][64 * 64];  // G^T rows h(local), cols i (swizzled), double-buffered

  // loop-invariant fragments: scT rows j (k=i), E rows j (k=d) — loaded ONCE per block
  bf16x8 aC1[2], aC2[2];
  {
    const size_t tb = (size_t)bc * 4096;
#pragma unroll
    for (int ks = 0; ks < 2; ++ks) {
      const int o = rj * 64 + (ks * 4 + quad) * 8;
      aC1[ks] = *(const bf16x8*)(scTg + tb + o);
      aC2[ks] = *(const bf16x8*)(Eg + tb + o);
    }
  }
  const short* Sp = STg + (size_t)bc * (Hh * Dd);

  float4 rGa[2], rGb[2];
  bf16x8 stF[4][2];
  auto load_G = [&](int tl) {
    const float* xr = bx + ((size_t)(b * Ll) + ch * Cc + 2 * ip) * Hh + tl * HC + hg * 8;
    rGa[0] = *(const float4*)(xr);
    rGa[1] = *(const float4*)(xr + 4);
    rGb[0] = *(const float4*)(xr + Hh);
    rGb[1] = *(const float4*)(xr + Hh + 4);
  };
  auto load_S = [&](int tl) {
#pragma unroll
    for (int ht = 0; ht < 4; ++ht) {
      const int h = tl * HC + ht * 16 + lq;
#pragma unroll
      for (int ks = 0; ks < 2; ++ks)
        stF[ht][ks] = *(const bf16x8*)(Sp + h * 64 + (ks * 4 + quad) * 8);
    }
  };

  load_G(tg * TG);
  load_S(tg * TG);

  const float s0 = (float)(ch * Cc + 2 * ip + 1), s1 = (float)(ch * Cc + 2 * ip + 2);

#pragma unroll
  for (int t = 0; t < TG; ++t) {
    const int tl = tg * TG + t;
    short* gbuf = sGT[t & 1];
    // stage G^T (scaled bx, h x i) from regs into LDS
    {
      const float A[8] = {rGa[0].x, rGa[0].y, rGa[0].z, rGa[0].w,
                          rGa[1].x, rGa[1].y, rGa[1].z, rGa[1].w};
      const float Bv[8] = {rGb[0].x, rGb[0].y, rGb[0].z, rGb[0].w,
                           rGb[1].x, rGb[1].y, rGb[1].z, rGb[1].w};
#pragma unroll
      for (int e = 0; e < 8; ++e) {
        const int hl = hg * 8 + e;
        const int sa = hl * 64 + (((ip >> 2) ^ (hl & 7)) << 3) + 2 * (ip & 3);
        *(unsigned*)&gbuf[sa] = pack2(A[e] * s0, Bv[e] * s1);
      }
    }
    if (t + 1 < TG) load_G(tl + 1);   // next tile's G in flight across the barrier
    sync_lds();                        // lgkm-only: global loads keep flying

#pragma unroll
    for (int ht = 0; ht < 4; ++ht) {
      const int rh = ht * 16 + lq;
      f32x4 accO = {};
#pragma unroll
      for (int ks = 0; ks < 2; ++ks) {
        const int blk = ((ks * 4 + quad) ^ (rh & 7)) << 3;
        const bf16x8 gv = *(const bf16x8*)&gbuf[rh * 64 + blk];
        accO = __builtin_amdgcn_mfma_f32_16x16x32_bf16(aC1[ks], gv, accO, 0, 0, 0);
        accO = __builtin_amdgcn_mfma_f32_16x16x32_bf16(aC2[ks], stF[ht][ks], accO, 0, 0, 0);
      }
#pragma unroll
      for (int r = 0; r < 4; ++r) {
        const int gj = ch * Cc + w * 16 + quad * 4 + r;
        const size_t off = ((size_t)(b * Ll) + gj) * Hh + tl * HC + ht * 16 + lq;
        out[off] = bx[off] + accO[r] * (1.0f / (float)(gj + 1));
      }
    }
    if (t + 1 < TG) load_S(tl + 1);   // stF regs free after MFMAs above
  }
}

extern "C" void kernel_launch(void* const* d_in, const int* in_sizes, int n_in,
                              void* d_out, int out_size, void* d_ws, size_t ws_size,
                              hipStream_t stream) {
  (void)in_sizes; (void)n_in; (void)out_size; (void)ws_size;
  const float* bx = (const float*)d_in[0];
  const int* x = (const int*)d_in[1];
  const float* ae = (const float*)d_in[2];
  const float* w = (const float*)d_in[3];
  float* out = (float*)d_out;
  short* Eg = (short*)d_ws;                        // 512*4096 bf16 = 4 MB
  short* scTg = Eg + (size_t)512 * 4096;           // 4 MB
  short* Sch = scTg + (size_t)512 * 4096;          // 512*768*64 bf16 = 50.3 MB (in-place -> STg)

  prep_kernel<<<Bb * NCH, 512, 0, stream>>>(x, ae, w, bx, Eg, scTg, Sch);
  prefix_kernel<<<Bb * 48, 256, 0, stream>>>(Sch);
  scan_kernel<<<NTG * Bb * NCH, 256, 0, stream>>>(bx, Eg, scTg, Sch, out);
}